// Round 2
// baseline (2060.969 us; speedup 1.0000x reference)
//
#include <hip/hip_runtime.h>
#include <stdint.h>

// ---------- types ----------
typedef __attribute__((ext_vector_type(8))) __bf16 bf16x8;
typedef __attribute__((ext_vector_type(4))) float f32x4;
typedef unsigned short u16;

__device__ __forceinline__ float bf2f(u16 u) {
  union { unsigned int i; float f; } x; x.i = ((unsigned int)u) << 16; return x.f;
}
__device__ __forceinline__ u16 f2bf(float f) {
  union { float f; unsigned int i; } x; x.f = f;
  unsigned int r = (x.i + 0x7fffu + ((x.i >> 16) & 1u)) >> 16;
  return (u16)r;
}

__device__ __forceinline__ void async16(void* lds, const void* g) {
  __builtin_amdgcn_global_load_lds((__attribute__((address_space(1))) void*)g,
                                   (__attribute__((address_space(3))) void*)lds,
                                   16, 0, 0);
}

// Non-temporal helpers: keep streaming traffic out of the XCD L2s so the
// GEMM weight/A panels stay resident (write-allocate thrash was evicting them).
__device__ __forceinline__ void nt_st_u16(u16* p, u16 v) { __builtin_nontemporal_store(v, p); }
__device__ __forceinline__ void nt_st_f32(float* p, float v) { __builtin_nontemporal_store(v, p); }
__device__ __forceinline__ u16 nt_ld_u16(const u16* p) { return __builtin_nontemporal_load(p); }
__device__ __forceinline__ float nt_ld_f32(const float* p) { return __builtin_nontemporal_load(p); }

// ---------- K0: dtype sniff. mode 0 = bf16, 1 = fp32. ----------
__global__ __launch_bounds__(256)
void sniff_k(const u16* __restrict__ x, int* __restrict__ flag) {
  __shared__ int cnt;
  if (threadIdx.x == 0) cnt = 0;
  __syncthreads();
  int good = 0;
  for (int i = threadIdx.x; i < 512; i += 256) {
    int e = (x[i] >> 7) & 0xFF;
    good += (e >= 110 && e <= 130) ? 1 : 0;
  }
  atomicAdd(&cnt, good);
  __syncthreads();
  if (threadIdx.x == 0) *flag = (cnt >= 448) ? 0 : 1;
}

// ---------- K0b: convert any input tensor to internal bf16 ----------
__global__ __launch_bounds__(256)
void conv_k(const void* __restrict__ src, u16* __restrict__ dst, int n,
            const int* __restrict__ flag) {
  const int md = *flag;
  int i = blockIdx.x * 256 + threadIdx.x;
  const int stride = gridDim.x * 256;
  if (md) {
    const float* s = (const float*)src;
    for (; i < n; i += stride) dst[i] = f2bf(s[i]);
  } else {
    const u16* s = (const u16*)src;
    for (; i < n; i += stride) dst[i] = s[i];
  }
}

// ---------- K1: ada = silu(c) @ ada_w^T + ada_b  (fp32 out, [8][4608]) ----------
__global__ __launch_bounds__(256)
void ada_k(const u16* __restrict__ c, const u16* __restrict__ aw,
           const u16* __restrict__ ab, float* __restrict__ ada) {
  int gw = blockIdx.x * 4 + (threadIdx.x >> 6);
  int lane = threadIdx.x & 63;
  int n = gw / 4608, j = gw - n * 4608;
  const u16* cr = c + n * 768;
  const u16* wr = aw + (long)j * 768;
  float s = 0.f;
#pragma unroll
  for (int i = 0; i < 12; i++) {
    int k = lane + i * 64;
    float cv = bf2f(cr[k]);
    cv = cv / (1.f + __expf(-cv));          // silu
    s += cv * bf2f(wr[k]);
  }
  for (int off = 32; off > 0; off >>= 1) s += __shfl_xor(s, off);
  if (lane == 0) ada[(long)n * 4608 + j] = s + bf2f(ab[j]);
}

// ---------- K2/K6: LayerNorm + modulate. ----------
template<int MODE>
__global__ __launch_bounds__(256)
void ln_mod(const void* __restrict__ src, const float* __restrict__ ada,
            u16* __restrict__ out, const int* __restrict__ flag) {
  const int md = (MODE == 0) ? *flag : 0;
  int m = blockIdx.x * 4 + (threadIdx.x >> 6);
  int lane = threadIdx.x & 63;
  int n; long soff;
  if (MODE == 0) {
    int b = m >> 6, t = m & 63;
    n = b >> 6;
    int wi = b & 63;
    int hh = ((wi >> 3) << 3) + (t >> 3);
    int ww = ((wi & 7) << 3) + (t & 7);
    int oh = (hh + 4) & 63, ow = (ww + 4) & 63;   // roll(-4)
    soff = ((long)n * 4096 + oh * 64 + ow) * 768;
  } else {
    n = m >> 12;
    soff = (long)m * 768;
  }
  const u16* su = (const u16*)src;
  const float* sf = (const float*)src;
  float vals[12];
  float s1 = 0.f, s2 = 0.f;
#pragma unroll
  for (int i = 0; i < 12; i++) {
    long idx = soff + lane + i * 64;
    float v = (MODE == 0 && md) ? sf[idx] : bf2f(su[idx]);
    vals[i] = v; s1 += v; s2 += v * v;
  }
  for (int off = 32; off > 0; off >>= 1) { s1 += __shfl_xor(s1, off); s2 += __shfl_xor(s2, off); }
  float mean = s1 * (1.f / 768.f);
  float var = s2 * (1.f / 768.f) - mean * mean;
  float rstd = rsqrtf(var + 1e-6f);
  const float* ap = ada + (long)n * 4608 + (MODE == 0 ? 0 : 2304);
#pragma unroll
  for (int i = 0; i < 12; i++) {
    int ch = lane + i * 64;
    float sh = ap[ch], sc = ap[768 + ch];
    nt_st_u16(out + (long)m * 768 + ch, f2bf((vals[i] - mean) * rstd * (1.f + sc) + sh));
  }
}

// ---------- GEMM: out = A(MxK) @ W(OxK)^T + bias.
// 256x256 tile, BK=64, 512 thr (8 waves 2Mx4N), 8-phase schedule (T3+T4),
// LDS 128KiB = 2 matrices x 2 dbuf x 2 khalf x [256][32] bf16 (16KB regions).
// XOR swizzle byte^=((byte>>7)&7)<<4 both-sides (pre-swizzled gload src +
// swizzled ds_read) kills the 8-way row-stride bank conflict (T2).
// Counted s_waitcnt vmcnt(8) twice per K-tile, never 0 in main loop (T4).
// s_setprio around MFMA cluster (T5). Chunked bijective XCD swizzle (T1).
// All epilogue output stores + residual stream loads are NON-TEMPORAL so the
// weight/A panels stay L2-resident during the GEMM (write-allocate thrash fix).
// ----------
__device__ __forceinline__ bf16x8 ldsRead(const char* region, int rowb, int quad) {
  int D = rowb * 64 + quad * 16;
  D ^= ((D >> 7) & 7) << 4;
  return *(const bf16x8*)(region + D);
}

__device__ __forceinline__ void stage_half(const u16* __restrict__ G, long row0,
                                           int K, int kbase, char* region,
                                           int wave, int tid) {
#pragma unroll
  for (int rr = 0; rr < 2; rr++) {
    const int D = rr * 8192 + tid * 16;
    const int S = D ^ (((D >> 7) & 7) << 4);   // inverse-swizzled source
    async16(region + rr * 8192 + wave * 1024,
            G + (row0 + (S >> 6)) * (long)K + (kbase + ((S & 63) >> 1)));
  }
}

__device__ __forceinline__ void ck8() { asm volatile("s_waitcnt vmcnt(8)"); }
__device__ __forceinline__ void ck4() { asm volatile("s_waitcnt vmcnt(4)"); }
__device__ __forceinline__ void ck0() { asm volatile("s_waitcnt vmcnt(0)"); }

#define MFMA_(a, b, c) __builtin_amdgcn_mfma_f32_16x16x32_bf16(a, b, c, 0, 0, 0)
#define NOP_ ((void)0)

#define PHASE(MH, AR, BR, STAGE_EXPR, CKPT_EXPR) do {                          \
    if ((MH) == 0) {                                                           \
      bf[0] = ldsRead((BR), wcb + 0  + l16, quad);                             \
      bf[1] = ldsRead((BR), wcb + 16 + l16, quad);                             \
      bf[2] = ldsRead((BR), wcb + 32 + l16, quad);                             \
      bf[3] = ldsRead((BR), wcb + 48 + l16, quad);                             \
    }                                                                          \
    bf16x8 af0 = ldsRead((AR), wrb + (MH)*64 + 0  + l16, quad);                \
    bf16x8 af1 = ldsRead((AR), wrb + (MH)*64 + 16 + l16, quad);                \
    bf16x8 af2 = ldsRead((AR), wrb + (MH)*64 + 32 + l16, quad);                \
    bf16x8 af3 = ldsRead((AR), wrb + (MH)*64 + 48 + l16, quad);                \
    STAGE_EXPR;                                                                \
    CKPT_EXPR;                                                                 \
    asm volatile("s_barrier" ::: "memory");                                    \
    asm volatile("s_waitcnt lgkmcnt(0)");                                      \
    __builtin_amdgcn_sched_barrier(0);                                         \
    __builtin_amdgcn_s_setprio(1);                                             \
    acc[(MH)*4+0][0] = MFMA_(af0, bf[0], acc[(MH)*4+0][0]);                    \
    acc[(MH)*4+0][1] = MFMA_(af0, bf[1], acc[(MH)*4+0][1]);                    \
    acc[(MH)*4+0][2] = MFMA_(af0, bf[2], acc[(MH)*4+0][2]);                    \
    acc[(MH)*4+0][3] = MFMA_(af0, bf[3], acc[(MH)*4+0][3]);                    \
    acc[(MH)*4+1][0] = MFMA_(af1, bf[0], acc[(MH)*4+1][0]);                    \
    acc[(MH)*4+1][1] = MFMA_(af1, bf[1], acc[(MH)*4+1][1]);                    \
    acc[(MH)*4+1][2] = MFMA_(af1, bf[2], acc[(MH)*4+1][2]);                    \
    acc[(MH)*4+1][3] = MFMA_(af1, bf[3], acc[(MH)*4+1][3]);                    \
    acc[(MH)*4+2][0] = MFMA_(af2, bf[0], acc[(MH)*4+2][0]);                    \
    acc[(MH)*4+2][1] = MFMA_(af2, bf[1], acc[(MH)*4+2][1]);                    \
    acc[(MH)*4+2][2] = MFMA_(af2, bf[2], acc[(MH)*4+2][2]);                    \
    acc[(MH)*4+2][3] = MFMA_(af2, bf[3], acc[(MH)*4+2][3]);                    \
    acc[(MH)*4+3][0] = MFMA_(af3, bf[0], acc[(MH)*4+3][0]);                    \
    acc[(MH)*4+3][1] = MFMA_(af3, bf[1], acc[(MH)*4+3][1]);                    \
    acc[(MH)*4+3][2] = MFMA_(af3, bf[2], acc[(MH)*4+3][2]);                    \
    acc[(MH)*4+3][3] = MFMA_(af3, bf[3], acc[(MH)*4+3][3]);                    \
    __builtin_amdgcn_s_setprio(0);                                             \
    __builtin_amdgcn_sched_barrier(0);                                         \
    asm volatile("s_barrier" ::: "memory");                                    \
  } while (0)

template<int EPI>
__global__ __launch_bounds__(512, 1)
void gemm_bt(const u16* __restrict__ A, const u16* __restrict__ W,
             const u16* __restrict__ bias, void* __restrict__ outb,
             int K, int O,
             const float* __restrict__ ada, const void* __restrict__ resid,
             long m0, const int* __restrict__ flag) {
  const int md = (EPI >= 2) ? *flag : 0;
  __shared__ __align__(16) u16 As[4 * 8192];   // 4 x 16KB khalf regions
  __shared__ __align__(16) u16 Bs[4 * 8192];
  const int tid = threadIdx.x;
  const int wave = tid >> 6, lane = tid & 63;
  const int quad = lane >> 4, l16 = lane & 15;
  const int wr = wave >> 2, wc = wave & 3;     // 2 M-warps x 4 N-warps
  const int wrb = wr * 128, wcb = wc * 64;

  // T1: chunked bijective XCD swizzle -> each XCD owns contiguous row-panels
  const int gx = gridDim.x;
  const int nwg = gx * (int)gridDim.y;
  int id = (int)blockIdx.y * gx + (int)blockIdx.x;
  {
    const int q8 = nwg >> 3, r8 = nwg & 7;
    const int xcd = id & 7, loc = id >> 3;
    id = (xcd < r8 ? xcd * (q8 + 1) : r8 * (q8 + 1) + (xcd - r8) * q8) + loc;
  }
  const int ty = id / gx, tx = id - ty * gx;
  const long tile_m = (long)ty * 256;
  const int tile_o = tx * 256;

  char* AsB = (char*)As;
  char* BsB = (char*)Bs;
  const int NKT = K >> 6;                      // K-tiles of 64 (>= 12 here)

  // ---- prologue: A0.kh0 B0.kh0 A0.kh1 B0.kh1 A1.kh0 B1.kh0 (12 loads) ----
  stage_half(A, tile_m, K, 0,  AsB + 0 * 16384, wave, tid);
  stage_half(W, tile_o, K, 0,  BsB + 0 * 16384, wave, tid);
  stage_half(A, tile_m, K, 32, AsB + 1 * 16384, wave, tid);
  stage_half(W, tile_o, K, 32, BsB + 1 * 16384, wave, tid);
  stage_half(A, tile_m, K, 64, AsB + 2 * 16384, wave, tid);
  stage_half(W, tile_o, K, 64, BsB + 2 * 16384, wave, tid);
  ck8();                                        // first 4 loads (tile0 kh0) landed
  asm volatile("s_barrier" ::: "memory");

  f32x4 acc[8][4] = {};
  bf16x8 bf[4];

  int t = 0;
  for (; t <= NKT - 3; ++t) {
    const int buf = t & 1;
    const char* Ar0 = AsB + ((buf << 1) | 0) * 16384;
    const char* Br0 = BsB + ((buf << 1) | 0) * 16384;
    const char* Ar1 = AsB + ((buf << 1) | 1) * 16384;
    const char* Br1 = BsB + ((buf << 1) | 1) * 16384;
    char* pa1 = AsB + (((buf ^ 1) << 1) | 1) * 16384;
    char* pb1 = BsB + (((buf ^ 1) << 1) | 1) * 16384;
    char* pa0 = AsB + ((buf << 1) | 0) * 16384;
    char* pb0 = BsB + ((buf << 1) | 0) * 16384;
    PHASE(0, Ar0, Br0, (stage_half(A, tile_m, K, (t + 1) * 64 + 32, pa1, wave, tid)), NOP_);
    PHASE(1, Ar0, Br0, (stage_half(W, tile_o, K, (t + 1) * 64 + 32, pb1, wave, tid)), ck8());
    PHASE(0, Ar1, Br1, (stage_half(A, tile_m, K, (t + 2) * 64,      pa0, wave, tid)), NOP_);
    PHASE(1, Ar1, Br1, (stage_half(W, tile_o, K, (t + 2) * 64,      pb0, wave, tid)), ck8());
  }
  {  // t == NKT-2: only kh1-of-last-tile stages remain
    const int buf = t & 1;
    const char* Ar0 = AsB + ((buf << 1) | 0) * 16384;
    const char* Br0 = BsB + ((buf << 1) | 0) * 16384;
    const char* Ar1 = AsB + ((buf << 1) | 1) * 16384;
    const char* Br1 = BsB + ((buf << 1) | 1) * 16384;
    char* pa1 = AsB + (((buf ^ 1) << 1) | 1) * 16384;
    char* pb1 = BsB + (((buf ^ 1) << 1) | 1) * 16384;
    PHASE(0, Ar0, Br0, (stage_half(A, tile_m, K, (t + 1) * 64 + 32, pa1, wave, tid)), NOP_);
    PHASE(1, Ar0, Br0, (stage_half(W, tile_o, K, (t + 1) * 64 + 32, pb1, wave, tid)), ck8());
    PHASE(0, Ar1, Br1, NOP_, NOP_);
    PHASE(1, Ar1, Br1, NOP_, ck4());
    t++;
  }
  {  // t == NKT-1: drain
    const int buf = t & 1;
    const char* Ar0 = AsB + ((buf << 1) | 0) * 16384;
    const char* Br0 = BsB + ((buf << 1) | 0) * 16384;
    const char* Ar1 = AsB + ((buf << 1) | 1) * 16384;
    const char* Br1 = BsB + ((buf << 1) | 1) * 16384;
    PHASE(0, Ar0, Br0, NOP_, NOP_);
    PHASE(1, Ar0, Br0, NOP_, ck0());
    PHASE(0, Ar1, Br1, NOP_, NOP_);
    PHASE(1, Ar1, Br1, NOP_, NOP_);
  }

  // ---- epilogue (all streaming traffic non-temporal) ----
  const long base_row = tile_m + wrb + quad * 4;
  const int base_col = tile_o + wcb + l16;
#pragma unroll
  for (int ni = 0; ni < 4; ni++) {
    const int col = base_col + ni * 16;
    const float bv = bf2f(bias[col]);
#pragma unroll
    for (int mi = 0; mi < 8; mi++) {
#pragma unroll
      for (int r = 0; r < 4; r++) {
        float v = acc[mi][ni][r] + bv;
        long m = base_row + mi * 16 + r;     // chunk-local row
        if (EPI == 0) {
          nt_st_u16((u16*)outb + m * O + col, f2bf(v));
        } else if (EPI == 1) {
          float tt = v + 0.044715f * v * v * v;
          float g = 0.5f * v * (1.f + tanhf(0.79788456080286536f * tt));
          nt_st_u16((u16*)outb + m * O + col, f2bf(g));
        } else if (EPI == 2) {
          int b = (int)(m >> 6), tk = (int)m & 63;
          int n = b >> 6, wi = b & 63;
          int hh = ((wi >> 3) << 3) + (tk >> 3);
          int ww = ((wi & 7) << 3) + (tk & 7);
          int oh = (hh + 4) & 63, ow = (ww + 4) & 63;
          long dst = ((long)n * 4096 + oh * 64 + ow) * 768 + col;
          float gm = ada[(long)n * 4608 + 1536 + col];
          float rv = md ? nt_ld_f32((const float*)resid + dst)
                        : bf2f(nt_ld_u16((const u16*)resid + dst));
          nt_st_u16((u16*)outb + dst, f2bf(rv + gm * v));
        } else {  // EPI 3
          long mg = m0 + m;                  // global row
          int n = (int)(mg >> 12);
          float gm = ada[(long)n * 4608 + 3840 + col];
          long dst = mg * 768 + col;
          float rv = bf2f(nt_ld_u16((const u16*)resid + dst));   // xres is internal bf16
          float ov = rv + gm * v;
          if (md) nt_st_f32((float*)outb + dst, ov);
          else    nt_st_u16((u16*)outb + dst, f2bf(ov));
        }
      }
    }
  }
}

// ---------- K4: window attention. block = (head, window-in-chunk) ----------
__global__ __launch_bounds__(256)
void attn_k(const u16* __restrict__ qkv, u16* __restrict__ out) {
  const int h = blockIdx.x, b = blockIdx.y;
  __shared__ u16 qs[64 * 66];
  __shared__ u16 kt[64 * 66];   // transposed: kt[d][t]
  __shared__ u16 vs[64 * 66];
  __shared__ float ps[64 * 65];
  const int tid = threadIdx.x;
  const u16* base = qkv + (long)b * 64 * 2304 + h * 64;
#pragma unroll
  for (int i = 0; i < 16; i++) {
    int t = (tid >> 6) + i * 4;
    int d = tid & 63;
    qs[t * 66 + d] = base[(long)t * 2304 + d];
    kt[d * 66 + t] = base[(long)t * 2304 + 768 + d];
    vs[t * 66 + d] = base[(long)t * 2304 + 1536 + d];
  }
  __syncthreads();
  const int r = tid >> 2, g = tid & 3;
  float s[16];
#pragma unroll
  for (int j = 0; j < 16; j++) s[j] = 0.f;
  for (int kk = 0; kk < 64; kk++) {
    float qv = bf2f(qs[r * 66 + kk]);
    const u16* krow = &kt[kk * 66 + g * 16];
#pragma unroll
    for (int j = 0; j < 16; j++) s[j] += qv * bf2f(krow[j]);
  }
  float mx = -1e30f;
#pragma unroll
  for (int j = 0; j < 16; j++) { s[j] *= 0.125f; mx = fmaxf(mx, s[j]); }
  mx = fmaxf(mx, __shfl_xor(mx, 1));
  mx = fmaxf(mx, __shfl_xor(mx, 2));
  float sum = 0.f;
#pragma unroll
  for (int j = 0; j < 16; j++) { s[j] = __expf(s[j] - mx); sum += s[j]; }
  sum += __shfl_xor(sum, 1);
  sum += __shfl_xor(sum, 2);
  float inv = 1.f / sum;
#pragma unroll
  for (int j = 0; j < 16; j++) ps[r * 65 + g * 16 + j] = s[j] * inv;
  __syncthreads();
  float o[16];
#pragma unroll
  for (int j = 0; j < 16; j++) o[j] = 0.f;
  for (int j = 0; j < 64; j++) {
    float pv = ps[r * 65 + j];
    const u16* vrow = &vs[j * 66 + g * 16];
#pragma unroll
    for (int d = 0; d < 16; d++) o[d] += pv * bf2f(vrow[d]);
  }
  u16* orow = out + ((long)b * 64 + r) * 768 + h * 64 + g * 16;
#pragma unroll
  for (int d = 0; d < 16; d++) nt_st_u16(orow + d, f2bf(o[d]));
}

// ---------- launch ----------
// Workspace layout (total 222,743,056 B):
//   ada  @ 0          : 147,456 B  fp32 [8][4608]
//   flag @ 147456     : 16 B
//   bufA @ 147472     : 50,331,648 B   (hmod -> atto -> h2)
//   bufB @ 50479120   : 100,663,296 B  (qkv chunk 16384x2304 / fc1 chunk 16384x3072)
//   xres @ 151142416  : 50,331,648 B
//   wbuf @ 201474064  : 21,268,992 B   (converted bf16: c + all weights/biases)
extern "C" void kernel_launch(void* const* d_in, const int* in_sizes, int n_in,
                              void* d_out, int out_size, void* d_ws, size_t ws_size,
                              hipStream_t stream) {
  const void* x_seq  = d_in[0];
  const void* c      = d_in[1];
  const void* qkv_w  = d_in[2];
  const void* qkv_b  = d_in[3];
  const void* proj_w = d_in[4];
  const void* proj_b = d_in[5];
  const void* fc1_w  = d_in[6];
  const void* fc1_b  = d_in[7];
  const void* fc2_w  = d_in[8];
  const void* fc2_b  = d_in[9];
  const void* ada_w  = d_in[10];
  const void* ada_b  = d_in[11];

  const size_t NEEDED = 222743056;
  if (ws_size < NEEDED) return;

  char* ws = (char*)d_ws;
  float* ada = (float*)(ws);
  int* flag  = (int*)(ws + 147456);
  u16* bufA  = (u16*)(ws + 147472);
  u16* bufB  = (u16*)(ws + 50479120);
  u16* xres  = (u16*)(ws + 151142416);
  u16* wbuf  = (u16*)(ws + 201474064);

  u16* w_c     = wbuf;                 // 6144
  u16* w_qkvw  = wbuf + 6144;          // 1769472
  u16* w_qkvb  = wbuf + 1775616;       // 2304
  u16* w_projw = wbuf + 1777920;       // 589824
  u16* w_projb = wbuf + 2367744;       // 768
  u16* w_fc1w  = wbuf + 2368512;       // 2359296
  u16* w_fc1b  = wbuf + 4727808;       // 3072
  u16* w_fc2w  = wbuf + 4730880;       // 2359296
  u16* w_fc2b  = wbuf + 7090176;       // 768
  u16* w_adaw  = wbuf + 7090944;       // 3538944
  u16* w_adab  = wbuf + 10629888;      // 4608

  sniff_k<<<1, 256, 0, stream>>>((const u16*)x_seq, flag);
  auto cv = [&](const void* s, u16* d, int n) {
    int blocks = (n + 2047) / 2048; if (blocks < 1) blocks = 1;
    conv_k<<<blocks, 256, 0, stream>>>(s, d, n, flag);
  };
  cv(c, w_c, 6144);
  cv(qkv_w, w_qkvw, 1769472);   cv(qkv_b, w_qkvb, 2304);
  cv(proj_w, w_projw, 589824);  cv(proj_b, w_projb, 768);
  cv(fc1_w, w_fc1w, 2359296);   cv(fc1_b, w_fc1b, 3072);
  cv(fc2_w, w_fc2w, 2359296);   cv(fc2_b, w_fc2b, 768);
  cv(ada_w, w_adaw, 3538944);   cv(ada_b, w_adab, 4608);

  ada_k<<<9216, 256, 0, stream>>>(w_c, w_adaw, w_adab, ada);
  // LN+modulate (shifted-window gather, flagged-dtype x_seq) -> bufA
  ln_mod<0><<<8192, 256, 0, stream>>>(x_seq, ada, bufA, flag);
  // qkv GEMM + attention, 2 chunks of 16384 rows (256 windows)
  for (int k2 = 0; k2 < 2; k2++) {
    const u16* hc = bufA + (long)k2 * 16384 * 768;
    gemm_bt<0><<<dim3(9, 64), 512, 0, stream>>>(hc, w_qkvw, w_qkvb, bufB,
                                                768, 2304, nullptr, nullptr, 0, flag);
    attn_k<<<dim3(12, 256), 256, 0, stream>>>(bufB, bufA + (long)k2 * 16384 * 768);
  }
  // proj GEMM + gated residual scatter -> xres (bf16)
  gemm_bt<2><<<dim3(3, 128), 512, 0, stream>>>(bufA, w_projw, w_projb, xres,
                                               768, 768, ada, x_seq, 0, flag);
  // LN+modulate (MLP) -> bufA
  ln_mod<1><<<8192, 256, 0, stream>>>(xres, ada, bufA, flag);
  // MLP in 2 chunks of 16384 rows
  for (int cidx = 0; cidx < 2; cidx++) {
    const u16* h2c = bufA + (long)cidx * 16384 * 768;
    gemm_bt<1><<<dim3(12, 64), 512, 0, stream>>>(h2c, w_fc1w, w_fc1b, bufB,
                                                 768, 3072, nullptr, nullptr, 0, flag);
    gemm_bt<3><<<dim3(3, 64), 512, 0, stream>>>(bufB, w_fc2w, w_fc2b, d_out,
                                                3072, 768, ada, xres,
                                                (long)cidx * 16384, flag);
  }
}

// Round 4
// 1385.216 us; speedup vs baseline: 1.4878x; 1.4878x over previous
//
#include <hip/hip_runtime.h>
#include <stdint.h>

// ---------- types ----------
typedef __attribute__((ext_vector_type(8))) __bf16 bf16x8;
typedef __attribute__((ext_vector_type(4))) float f32x4;
typedef __attribute__((ext_vector_type(4))) unsigned short u16x4;
typedef unsigned short u16;

__device__ __forceinline__ float bf2f(u16 u) {
  union { unsigned int i; float f; } x; x.i = ((unsigned int)u) << 16; return x.f;
}
__device__ __forceinline__ u16 f2bf(float f) {
  union { float f; unsigned int i; } x; x.f = f;
  unsigned int r = (x.i + 0x7fffu + ((x.i >> 16) & 1u)) >> 16;
  return (u16)r;
}

__device__ __forceinline__ void async16(void* lds, const void* g) {
  __builtin_amdgcn_global_load_lds((__attribute__((address_space(1))) void*)g,
                                   (__attribute__((address_space(3))) void*)lds,
                                   16, 0, 0);
}

// ---------- K0: dtype sniff. mode 0 = bf16, 1 = fp32. ----------
__global__ __launch_bounds__(256)
void sniff_k(const u16* __restrict__ x, int* __restrict__ flag) {
  __shared__ int cnt;
  if (threadIdx.x == 0) cnt = 0;
  __syncthreads();
  int good = 0;
  for (int i = threadIdx.x; i < 512; i += 256) {
    int e = (x[i] >> 7) & 0xFF;
    good += (e >= 110 && e <= 130) ? 1 : 0;
  }
  atomicAdd(&cnt, good);
  __syncthreads();
  if (threadIdx.x == 0) *flag = (cnt >= 448) ? 0 : 1;
}

// ---------- K0b: convert any input tensor to internal bf16 ----------
__global__ __launch_bounds__(256)
void conv_k(const void* __restrict__ src, u16* __restrict__ dst, int n,
            const int* __restrict__ flag) {
  const int md = *flag;
  int i = blockIdx.x * 256 + threadIdx.x;
  const int stride = gridDim.x * 256;
  if (md) {
    const float* s = (const float*)src;
    for (; i < n; i += stride) dst[i] = f2bf(s[i]);
  } else {
    const u16* s = (const u16*)src;
    for (; i < n; i += stride) dst[i] = s[i];
  }
}

// ---------- K1: ada = silu(c) @ ada_w^T + ada_b  (fp32 out, [8][4608]) ----------
__global__ __launch_bounds__(256)
void ada_k(const u16* __restrict__ c, const u16* __restrict__ aw,
           const u16* __restrict__ ab, float* __restrict__ ada) {
  int gw = blockIdx.x * 4 + (threadIdx.x >> 6);
  int lane = threadIdx.x & 63;
  int n = gw / 4608, j = gw - n * 4608;
  const u16* cr = c + n * 768;
  const u16* wr = aw + (long)j * 768;
  float s = 0.f;
#pragma unroll
  for (int i = 0; i < 12; i++) {
    int k = lane + i * 64;
    float cv = bf2f(cr[k]);
    cv = cv / (1.f + __expf(-cv));          // silu
    s += cv * bf2f(wr[k]);
  }
  for (int off = 32; off > 0; off >>= 1) s += __shfl_xor(s, off);
  if (lane == 0) ada[(long)n * 4608 + j] = s + bf2f(ab[j]);
}

// ---------- K2/K6: LayerNorm + modulate. ----------
template<int MODE>
__global__ __launch_bounds__(256)
void ln_mod(const void* __restrict__ src, const float* __restrict__ ada,
            u16* __restrict__ out, const int* __restrict__ flag) {
  const int md = (MODE == 0) ? *flag : 0;
  int m = blockIdx.x * 4 + (threadIdx.x >> 6);
  int lane = threadIdx.x & 63;
  int n; long soff;
  if (MODE == 0) {
    int b = m >> 6, t = m & 63;
    n = b >> 6;
    int wi = b & 63;
    int hh = ((wi >> 3) << 3) + (t >> 3);
    int ww = ((wi & 7) << 3) + (t & 7);
    int oh = (hh + 4) & 63, ow = (ww + 4) & 63;   // roll(-4)
    soff = ((long)n * 4096 + oh * 64 + ow) * 768;
  } else {
    n = m >> 12;
    soff = (long)m * 768;
  }
  const u16* su = (const u16*)src;
  const float* sf = (const float*)src;
  float vals[12];
  float s1 = 0.f, s2 = 0.f;
#pragma unroll
  for (int i = 0; i < 12; i++) {
    long idx = soff + lane + i * 64;
    float v = (MODE == 0 && md) ? sf[idx] : bf2f(su[idx]);
    vals[i] = v; s1 += v; s2 += v * v;
  }
  for (int off = 32; off > 0; off >>= 1) { s1 += __shfl_xor(s1, off); s2 += __shfl_xor(s2, off); }
  float mean = s1 * (1.f / 768.f);
  float var = s2 * (1.f / 768.f) - mean * mean;
  float rstd = rsqrtf(var + 1e-6f);
  const float* ap = ada + (long)n * 4608 + (MODE == 0 ? 0 : 2304);
#pragma unroll
  for (int i = 0; i < 12; i++) {
    int ch = lane + i * 64;
    float sh = ap[ch], sc = ap[768 + ch];
    out[(long)m * 768 + ch] = f2bf((vals[i] - mean) * rstd * (1.f + sc) + sh);
  }
}

// ---------- GEMM: out = A(MxK) @ W(OxK)^T + bias.
// 256x256 tile, BK=64, 512 thr (8 waves 2Mx4N), 8-phase schedule (T3+T4),
// LDS 128KiB = 2 matrices x 2 dbuf x 2 khalf x [256][32] bf16 (16KB regions).
// XOR swizzle byte^=((byte>>7)&7)<<4 both-sides kills staging bank conflicts (T2).
// Counted s_waitcnt vmcnt(8) twice per K-tile, never 0 in main loop (T4).
// s_setprio around MFMA cluster (T5). Chunked bijective XCD swizzle (T1).
// EPILOGUE: LDS-transpose (reusing As/Bs as fp32 staging, 2x 128-row passes)
// -> 8B-per-lane, 512B-per-row-contiguous NON-TEMPORAL stores. Full-line NT
// gives the round-2 fetch reduction (no write-allocate thrash of W/A panels)
// WITHOUT the round-2 partial-line RMW write amplification.
// ----------
__device__ __forceinline__ bf16x8 ldsRead(const char* region, int rowb, int quad) {
  int D = rowb * 64 + quad * 16;
  D ^= ((D >> 7) & 7) << 4;
  return *(const bf16x8*)(region + D);
}

__device__ __forceinline__ void stage_half(const u16* __restrict__ G, long row0,
                                           int K, int kbase, char* region,
                                           int wave, int tid) {
#pragma unroll
  for (int rr = 0; rr < 2; rr++) {
    const int D = rr * 8192 + tid * 16;
    const int S = D ^ (((D >> 7) & 7) << 4);   // inverse-swizzled source
    async16(region + rr * 8192 + wave * 1024,
            G + (row0 + (S >> 6)) * (long)K + (kbase + ((S & 63) >> 1)));
  }
}

__device__ __forceinline__ void ck8() { asm volatile("s_waitcnt vmcnt(8)"); }
__device__ __forceinline__ void ck4() { asm volatile("s_waitcnt vmcnt(4)"); }
__device__ __forceinline__ void ck0() { asm volatile("s_waitcnt vmcnt(0)"); }

#define MFMA_(a, b, c) __builtin_amdgcn_mfma_f32_16x16x32_bf16(a, b, c, 0, 0, 0)
#define NOP_ ((void)0)

#define PHASE(MH, AR, BR, STAGE_EXPR, CKPT_EXPR) do {                          \
    if ((MH) == 0) {                                                           \
      bf[0] = ldsRead((BR), wcb + 0  + l16, quad);                             \
      bf[1] = ldsRead((BR), wcb + 16 + l16, quad);                             \
      bf[2] = ldsRead((BR), wcb + 32 + l16, quad);                             \
      bf[3] = ldsRead((BR), wcb + 48 + l16, quad);                             \
    }                                                                          \
    bf16x8 af0 = ldsRead((AR), wrb + (MH)*64 + 0  + l16, quad);                \
    bf16x8 af1 = ldsRead((AR), wrb + (MH)*64 + 16 + l16, quad);                \
    bf16x8 af2 = ldsRead((AR), wrb + (MH)*64 + 32 + l16, quad);                \
    bf16x8 af3 = ldsRead((AR), wrb + (MH)*64 + 48 + l16, quad);                \
    STAGE_EXPR;                                                                \
    CKPT_EXPR;                                                                 \
    asm volatile("s_barrier" ::: "memory");                                    \
    asm volatile("s_waitcnt lgkmcnt(0)");                                      \
    __builtin_amdgcn_sched_barrier(0);                                         \
    __builtin_amdgcn_s_setprio(1);                                             \
    acc[(MH)*4+0][0] = MFMA_(af0, bf[0], acc[(MH)*4+0][0]);                    \
    acc[(MH)*4+0][1] = MFMA_(af0, bf[1], acc[(MH)*4+0][1]);                    \
    acc[(MH)*4+0][2] = MFMA_(af0, bf[2], acc[(MH)*4+0][2]);                    \
    acc[(MH)*4+0][3] = MFMA_(af0, bf[3], acc[(MH)*4+0][3]);                    \
    acc[(MH)*4+1][0] = MFMA_(af1, bf[0], acc[(MH)*4+1][0]);                    \
    acc[(MH)*4+1][1] = MFMA_(af1, bf[1], acc[(MH)*4+1][1]);                    \
    acc[(MH)*4+1][2] = MFMA_(af1, bf[2], acc[(MH)*4+1][2]);                    \
    acc[(MH)*4+1][3] = MFMA_(af1, bf[3], acc[(MH)*4+1][3]);                    \
    acc[(MH)*4+2][0] = MFMA_(af2, bf[0], acc[(MH)*4+2][0]);                    \
    acc[(MH)*4+2][1] = MFMA_(af2, bf[1], acc[(MH)*4+2][1]);                    \
    acc[(MH)*4+2][2] = MFMA_(af2, bf[2], acc[(MH)*4+2][2]);                    \
    acc[(MH)*4+2][3] = MFMA_(af2, bf[3], acc[(MH)*4+2][3]);                    \
    acc[(MH)*4+3][0] = MFMA_(af3, bf[0], acc[(MH)*4+3][0]);                    \
    acc[(MH)*4+3][1] = MFMA_(af3, bf[1], acc[(MH)*4+3][1]);                    \
    acc[(MH)*4+3][2] = MFMA_(af3, bf[2], acc[(MH)*4+3][2]);                    \
    acc[(MH)*4+3][3] = MFMA_(af3, bf[3], acc[(MH)*4+3][3]);                    \
    __builtin_amdgcn_s_setprio(0);                                             \
    __builtin_amdgcn_sched_barrier(0);                                         \
    asm volatile("s_barrier" ::: "memory");                                    \
  } while (0)

template<int EPI>
__global__ __launch_bounds__(512, 1)
void gemm_bt(const u16* __restrict__ A, const u16* __restrict__ W,
             const u16* __restrict__ bias, void* __restrict__ outb,
             int K, int O,
             const float* __restrict__ ada, const void* __restrict__ resid,
             long m0, const int* __restrict__ flag) {
  const int md = (EPI >= 2) ? *flag : 0;
  __shared__ __align__(16) u16 As[4 * 8192];   // 4 x 16KB khalf regions
  __shared__ __align__(16) u16 Bs[4 * 8192];
  const int tid = threadIdx.x;
  const int wave = tid >> 6, lane = tid & 63;
  const int quad = lane >> 4, l16 = lane & 15;
  const int wr = wave >> 2, wc = wave & 3;     // 2 M-warps x 4 N-warps
  const int wrb = wr * 128, wcb = wc * 64;

  // T1: chunked bijective XCD swizzle -> each XCD owns contiguous row-panels
  const int gx = gridDim.x;
  const int nwg = gx * (int)gridDim.y;
  int id = (int)blockIdx.y * gx + (int)blockIdx.x;
  {
    const int q8 = nwg >> 3, r8 = nwg & 7;
    const int xcd = id & 7, loc = id >> 3;
    id = (xcd < r8 ? xcd * (q8 + 1) : r8 * (q8 + 1) + (xcd - r8) * q8) + loc;
  }
  const int ty = id / gx, tx = id - ty * gx;
  const long tile_m = (long)ty * 256;
  const int tile_o = tx * 256;

  char* AsB = (char*)As;
  char* BsB = (char*)Bs;
  const int NKT = K >> 6;                      // K-tiles of 64 (>= 12 here)

  // ---- prologue: A0.kh0 B0.kh0 A0.kh1 B0.kh1 A1.kh0 B1.kh0 (12 loads) ----
  stage_half(A, tile_m, K, 0,  AsB + 0 * 16384, wave, tid);
  stage_half(W, tile_o, K, 0,  BsB + 0 * 16384, wave, tid);
  stage_half(A, tile_m, K, 32, AsB + 1 * 16384, wave, tid);
  stage_half(W, tile_o, K, 32, BsB + 1 * 16384, wave, tid);
  stage_half(A, tile_m, K, 64, AsB + 2 * 16384, wave, tid);
  stage_half(W, tile_o, K, 64, BsB + 2 * 16384, wave, tid);
  ck8();                                        // first 4 loads (tile0 kh0) landed
  asm volatile("s_barrier" ::: "memory");

  f32x4 acc[8][4] = {};
  bf16x8 bf[4];

  int t = 0;
  for (; t <= NKT - 3; ++t) {
    const int buf = t & 1;
    const char* Ar0 = AsB + ((buf << 1) | 0) * 16384;
    const char* Br0 = BsB + ((buf << 1) | 0) * 16384;
    const char* Ar1 = AsB + ((buf << 1) | 1) * 16384;
    const char* Br1 = BsB + ((buf << 1) | 1) * 16384;
    char* pa1 = AsB + (((buf ^ 1) << 1) | 1) * 16384;
    char* pb1 = BsB + (((buf ^ 1) << 1) | 1) * 16384;
    char* pa0 = AsB + ((buf << 1) | 0) * 16384;
    char* pb0 = BsB + ((buf << 1) | 0) * 16384;
    PHASE(0, Ar0, Br0, (stage_half(A, tile_m, K, (t + 1) * 64 + 32, pa1, wave, tid)), NOP_);
    PHASE(1, Ar0, Br0, (stage_half(W, tile_o, K, (t + 1) * 64 + 32, pb1, wave, tid)), ck8());
    PHASE(0, Ar1, Br1, (stage_half(A, tile_m, K, (t + 2) * 64,      pa0, wave, tid)), NOP_);
    PHASE(1, Ar1, Br1, (stage_half(W, tile_o, K, (t + 2) * 64,      pb0, wave, tid)), ck8());
  }
  {  // t == NKT-2: only kh1-of-last-tile stages remain
    const int buf = t & 1;
    const char* Ar0 = AsB + ((buf << 1) | 0) * 16384;
    const char* Br0 = BsB + ((buf << 1) | 0) * 16384;
    const char* Ar1 = AsB + ((buf << 1) | 1) * 16384;
    const char* Br1 = BsB + ((buf << 1) | 1) * 16384;
    char* pa1 = AsB + (((buf ^ 1) << 1) | 1) * 16384;
    char* pb1 = BsB + (((buf ^ 1) << 1) | 1) * 16384;
    PHASE(0, Ar0, Br0, (stage_half(A, tile_m, K, (t + 1) * 64 + 32, pa1, wave, tid)), NOP_);
    PHASE(1, Ar0, Br0, (stage_half(W, tile_o, K, (t + 1) * 64 + 32, pb1, wave, tid)), ck8());
    PHASE(0, Ar1, Br1, NOP_, NOP_);
    PHASE(1, Ar1, Br1, NOP_, ck4());
    t++;
  }
  {  // t == NKT-1: drain
    const int buf = t & 1;
    const char* Ar0 = AsB + ((buf << 1) | 0) * 16384;
    const char* Br0 = BsB + ((buf << 1) | 0) * 16384;
    const char* Ar1 = AsB + ((buf << 1) | 1) * 16384;
    const char* Br1 = BsB + ((buf << 1) | 1) * 16384;
    PHASE(0, Ar0, Br0, NOP_, NOP_);
    PHASE(1, Ar0, Br0, NOP_, ck0());
    PHASE(0, Ar1, Br1, NOP_, NOP_);
    PHASE(1, Ar1, Br1, NOP_, NOP_);
  }

  // ---- epilogue: LDS transpose (fp32) -> wide full-line NT stores ----
  // Slab pass p covers tile rows [p*128, p*128+128). fp32 staging:
  // rows 0..63 in As (64KB), rows 64..127 in Bs. addr_dw = (row&63)*256 + colS,
  // colS = col ^ (quad(row)<<4)  (quad(row) = (row>>2)&3): 2-way banks = free.
  float* sAf = (float*)As;
  float* sBf = (float*)Bs;
  const int colq = lane * 4;                      // lane's 4 consecutive cols
  const int gcol = tile_o + colq;
  const u16x4 bq = *(const u16x4*)&bias[gcol];    // cached, tiny, reused
#pragma unroll
  for (int p = 0; p < 2; p++) {
    if (p) asm volatile("s_barrier" ::: "memory");   // pass-0 reads done
    if (wr == p) {
#pragma unroll
      for (int mi = 0; mi < 8; mi++) {
        float* rg = (mi < 4) ? sAf : sBf;
#pragma unroll
        for (int ni = 0; ni < 4; ni++) {
#pragma unroll
          for (int r = 0; r < 4; r++) {
            const int row = mi * 16 + quad * 4 + r;        // 0..127 slab-rel
            const int colS = (wcb + ni * 16 + l16) ^ (quad << 4);
            rg[((row & 63) << 8) + colS] = acc[mi][ni][r];
          }
        }
      }
    }
    asm volatile("s_waitcnt lgkmcnt(0)" ::: "memory");
    asm volatile("s_barrier" ::: "memory");
#pragma unroll
    for (int it = 0; it < 16; it++) {
      const int row = it * 8 + wave;                       // 0..127 slab-rel
      const float* rg = (row < 64) ? sAf : sBf;
      const int colS = colq ^ (((row >> 2) & 3) << 4);
      f32x4 v4 = *(const f32x4*)&rg[((row & 63) << 8) + colS];
      const long mrow = tile_m + (long)p * 128 + row;      // chunk-local row
      float vv[4];
#pragma unroll
      for (int j = 0; j < 4; j++) vv[j] = v4[j] + bf2f(bq[j]);
      if (EPI == 0) {
        u16x4 o4;
#pragma unroll
        for (int j = 0; j < 4; j++) o4[j] = f2bf(vv[j]);
        __builtin_nontemporal_store(o4, (u16x4*)((u16*)outb + mrow * O + gcol));
      } else if (EPI == 1) {
        u16x4 o4;
#pragma unroll
        for (int j = 0; j < 4; j++) {
          float v = vv[j];
          float tt = v + 0.044715f * v * v * v;
          o4[j] = f2bf(0.5f * v * (1.f + tanhf(0.79788456080286536f * tt)));
        }
        __builtin_nontemporal_store(o4, (u16x4*)((u16*)outb + mrow * O + gcol));
      } else if (EPI == 2) {
        const int m = (int)mrow;
        const int b = m >> 6, tk = m & 63;
        const int n = b >> 6, wi = b & 63;
        const int hh = ((wi >> 3) << 3) + (tk >> 3);
        const int ww = ((wi & 7) << 3) + (tk & 7);
        const int oh = (hh + 4) & 63, ow = (ww + 4) & 63;
        const long dst = ((long)n * 4096 + oh * 64 + ow) * 768 + gcol;
        const f32x4 gm = *(const f32x4*)&ada[(long)n * 4608 + 1536 + gcol];
        u16x4 o4;
        if (md) {
          f32x4 rv = __builtin_nontemporal_load((const f32x4*)((const float*)resid + dst));
#pragma unroll
          for (int j = 0; j < 4; j++) o4[j] = f2bf(rv[j] + gm[j] * vv[j]);
        } else {
          u16x4 rv = __builtin_nontemporal_load((const u16x4*)((const u16*)resid + dst));
#pragma unroll
          for (int j = 0; j < 4; j++) o4[j] = f2bf(bf2f(rv[j]) + gm[j] * vv[j]);
        }
        __builtin_nontemporal_store(o4, (u16x4*)((u16*)outb + dst));
      } else {  // EPI 3
        const long mg = m0 + mrow;
        const int n = (int)(mg >> 12);
        const long dst = mg * 768 + gcol;
        const f32x4 gm = *(const f32x4*)&ada[(long)n * 4608 + 3840 + gcol];
        u16x4 rv = __builtin_nontemporal_load((const u16x4*)((const u16*)resid + dst));
        if (md) {
          f32x4 ov;
#pragma unroll
          for (int j = 0; j < 4; j++) ov[j] = bf2f(rv[j]) + gm[j] * vv[j];
          __builtin_nontemporal_store(ov, (f32x4*)((float*)outb + dst));
        } else {
          u16x4 o4;
#pragma unroll
          for (int j = 0; j < 4; j++) o4[j] = f2bf(bf2f(rv[j]) + gm[j] * vv[j]);
          __builtin_nontemporal_store(o4, (u16x4*)((u16*)outb + dst));
        }
      }
    }
  }
}

// ---------- K4: window attention. block = (head, window-in-chunk) ----------
__global__ __launch_bounds__(256)
void attn_k(const u16* __restrict__ qkv, u16* __restrict__ out) {
  const int h = blockIdx.x, b = blockIdx.y;
  __shared__ u16 qs[64 * 66];
  __shared__ u16 kt[64 * 66];   // transposed: kt[d][t]
  __shared__ u16 vs[64 * 66];
  __shared__ float ps[64 * 65];
  const int tid = threadIdx.x;
  const u16* base = qkv + (long)b * 64 * 2304 + h * 64;
#pragma unroll
  for (int i = 0; i < 16; i++) {
    int t = (tid >> 6) + i * 4;
    int d = tid & 63;
    qs[t * 66 + d] = base[(long)t * 2304 + d];
    kt[d * 66 + t] = base[(long)t * 2304 + 768 + d];
    vs[t * 66 + d] = base[(long)t * 2304 + 1536 + d];
  }
  __syncthreads();
  const int r = tid >> 2, g = tid & 3;
  float s[16];
#pragma unroll
  for (int j = 0; j < 16; j++) s[j] = 0.f;
  for (int kk = 0; kk < 64; kk++) {
    float qv = bf2f(qs[r * 66 + kk]);
    const u16* krow = &kt[kk * 66 + g * 16];
#pragma unroll
    for (int j = 0; j < 16; j++) s[j] += qv * bf2f(krow[j]);
  }
  float mx = -1e30f;
#pragma unroll
  for (int j = 0; j < 16; j++) { s[j] *= 0.125f; mx = fmaxf(mx, s[j]); }
  mx = fmaxf(mx, __shfl_xor(mx, 1));
  mx = fmaxf(mx, __shfl_xor(mx, 2));
  float sum = 0.f;
#pragma unroll
  for (int j = 0; j < 16; j++) { s[j] = __expf(s[j] - mx); sum += s[j]; }
  sum += __shfl_xor(sum, 1);
  sum += __shfl_xor(sum, 2);
  float inv = 1.f / sum;
#pragma unroll
  for (int j = 0; j < 16; j++) ps[r * 65 + g * 16 + j] = s[j] * inv;
  __syncthreads();
  float o[16];
#pragma unroll
  for (int j = 0; j < 16; j++) o[j] = 0.f;
  for (int j = 0; j < 64; j++) {
    float pv = ps[r * 65 + j];
    const u16* vrow = &vs[j * 66 + g * 16];
#pragma unroll
    for (int d = 0; d < 16; d++) o[d] += pv * bf2f(vrow[d]);
  }
  u16* orow = out + ((long)b * 64 + r) * 768 + h * 64 + g * 16;
#pragma unroll
  for (int d = 0; d < 16; d++) orow[d] = f2bf(o[d]);
}

// ---------- launch ----------
// Workspace layout (total 222,743,056 B):
//   ada  @ 0          : 147,456 B  fp32 [8][4608]
//   flag @ 147456     : 16 B
//   bufA @ 147472     : 50,331,648 B   (hmod -> atto -> h2)
//   bufB @ 50479120   : 100,663,296 B  (qkv chunk 16384x2304 / fc1 chunk 16384x3072)
//   xres @ 151142416  : 50,331,648 B
//   wbuf @ 201474064  : 21,268,992 B   (converted bf16: c + all weights/biases)
extern "C" void kernel_launch(void* const* d_in, const int* in_sizes, int n_in,
                              void* d_out, int out_size, void* d_ws, size_t ws_size,
                              hipStream_t stream) {
  const void* x_seq  = d_in[0];
  const void* c      = d_in[1];
  const void* qkv_w  = d_in[2];
  const void* qkv_b  = d_in[3];
  const void* proj_w = d_in[4];
  const void* proj_b = d_in[5];
  const void* fc1_w  = d_in[6];
  const void* fc1_b  = d_in[7];
  const void* fc2_w  = d_in[8];
  const void* fc2_b  = d_in[9];
  const void* ada_w  = d_in[10];
  const void* ada_b  = d_in[11];

  const size_t NEEDED = 222743056;
  if (ws_size < NEEDED) return;

  char* ws = (char*)d_ws;
  float* ada = (float*)(ws);
  int* flag  = (int*)(ws + 147456);
  u16* bufA  = (u16*)(ws + 147472);
  u16* bufB  = (u16*)(ws + 50479120);
  u16* xres  = (u16*)(ws + 151142416);
  u16* wbuf  = (u16*)(ws + 201474064);

  u16* w_c     = wbuf;                 // 6144
  u16* w_qkvw  = wbuf + 6144;          // 1769472
  u16* w_qkvb  = wbuf + 1775616;       // 2304
  u16* w_projw = wbuf + 1777920;       // 589824
  u16* w_projb = wbuf + 2367744;       // 768
  u16* w_fc1w  = wbuf + 2368512;       // 2359296
  u16* w_fc1b  = wbuf + 4727808;       // 3072
  u16* w_fc2w  = wbuf + 4730880;       // 2359296
  u16* w_fc2b  = wbuf + 7090176;       // 768
  u16* w_adaw  = wbuf + 7090944;       // 3538944
  u16* w_adab  = wbuf + 10629888;      // 4608

  sniff_k<<<1, 256, 0, stream>>>((const u16*)x_seq, flag);
  auto cv = [&](const void* s, u16* d, int n) {
    int blocks = (n + 2047) / 2048; if (blocks < 1) blocks = 1;
    conv_k<<<blocks, 256, 0, stream>>>(s, d, n, flag);
  };
  cv(c, w_c, 6144);
  cv(qkv_w, w_qkvw, 1769472);   cv(qkv_b, w_qkvb, 2304);
  cv(proj_w, w_projw, 589824);  cv(proj_b, w_projb, 768);
  cv(fc1_w, w_fc1w, 2359296);   cv(fc1_b, w_fc1b, 3072);
  cv(fc2_w, w_fc2w, 2359296);   cv(fc2_b, w_fc2b, 768);
  cv(ada_w, w_adaw, 3538944);   cv(ada_b, w_adab, 4608);

  ada_k<<<9216, 256, 0, stream>>>(w_c, w_adaw, w_adab, ada);
  // LN+modulate (shifted-window gather, flagged-dtype x_seq) -> bufA
  ln_mod<0><<<8192, 256, 0, stream>>>(x_seq, ada, bufA, flag);
  // qkv GEMM + attention, 2 chunks of 16384 rows (256 windows)
  for (int k2 = 0; k2 < 2; k2++) {
    const u16* hc = bufA + (long)k2 * 16384 * 768;
    gemm_bt<0><<<dim3(9, 64), 512, 0, stream>>>(hc, w_qkvw, w_qkvb, bufB,
                                                768, 2304, nullptr, nullptr, 0, flag);
    attn_k<<<dim3(12, 256), 256, 0, stream>>>(bufB, bufA + (long)k2 * 16384 * 768);
  }
  // proj GEMM + gated residual scatter -> xres (bf16)
  gemm_bt<2><<<dim3(3, 128), 512, 0, stream>>>(bufA, w_projw, w_projb, xres,
                                               768, 768, ada, x_seq, 0, flag);
  // LN+modulate (MLP) -> bufA
  ln_mod<1><<<8192, 256, 0, stream>>>(xres, ada, bufA, flag);
  // MLP in 2 chunks of 16384 rows
  for (int cidx = 0; cidx < 2; cidx++) {
    const u16* h2c = bufA + (long)cidx * 16384 * 768;
    gemm_bt<1><<<dim3(12, 64), 512, 0, stream>>>(h2c, w_fc1w, w_fc1b, bufB,
                                                 768, 3072, nullptr, nullptr, 0, flag);
    gemm_bt<3><<<dim3(3, 64), 512, 0, stream>>>(bufB, w_fc2w, w_fc2b, d_out,
                                                3072, 768, ada, xres,
                                                (long)cidx * 16384, flag);
  }
}